// Round 1
// baseline (165.229 us; speedup 1.0000x reference)
//
#include <hip/hip_runtime.h>

#define DIMN 64
#define NNB 16
#define NREL 33

__global__ __launch_bounds__(64, 4)
void kgs_kernel(const int* __restrict__ u, const int* __restrict__ v,
                const int* __restrict__ adj, const int* __restrict__ rel_adj,
                const float* __restrict__ usr_emb, const float* __restrict__ ent_emb,
                const float* __restrict__ rel_emb,
                const float* __restrict__ W0, const float* __restrict__ b0,
                const float* __restrict__ W1, const float* __restrict__ b1,
                float* __restrict__ out)
{
    const int b = blockIdx.x;
    const int d = threadIdx.x;      // lane = output dim
    const int n16 = d & 15;         // neighbor slot within group-of-16

    __shared__ __align__(16) float user_sh[DIMN];
    __shared__ float ur[NREL + 3];          // ur[r] = dot(user, rel_emb[r])
    __shared__ float sv_sh[NNB * DIMN];     // ent_emb rows of hop-1 entities
    __shared__ float h1_sh[NNB * DIMN];     // iter0/hop1 outputs

    const int uu = u[b];
    const int vv = v[b];

    const float user_d = usr_emb[uu * DIMN + d];
    user_sh[d] = user_d;
    __syncthreads();

    // ---- precompute ur[r]: 33 user·rel dots (collapses all attention scores to lookups)
    if (d < NREL) {
        const float* re = rel_emb + d * DIMN;
        float acc = 0.f;
        #pragma unroll
        for (int k = 0; k < DIMN; k += 4) {
            const float4 uk = *(const float4*)(user_sh + k);
            const float4 rk = *(const float4*)(re + k);
            acc = fmaf(uk.x, rk.x, acc);
            acc = fmaf(uk.y, rk.y, acc);
            acc = fmaf(uk.z, rk.z, acc);
            acc = fmaf(uk.w, rk.w, acc);
        }
        ur[d] = acc;
    }
    __syncthreads();

    // ---- W0 column d into registers
    float w[DIMN];
    #pragma unroll
    for (int k = 0; k < DIMN; ++k) w[k] = W0[k * DIMN + d];
    const float b0d = b0[d];

    // hop-1 entity/relation indices: lane holds slot n16 (replicated 4x across wave)
    const int e1n = adj[vv * NNB + n16];
    const int r1n = rel_adj[vv * NNB + n16];

    // ================= iter 0, hop 1: h1[m], m = 0..15 =================
    for (int m = 0; m < NNB; ++m) {
        const int em = __builtin_amdgcn_readlane(e1n, m);   // uniform entity id
        const float sv = ent_emb[em * DIMN + d];
        sv_sh[m * DIMN + d] = sv;

        const int e2n = adj[em * NNB + n16];
        const int r2n = rel_adj[em * NNB + n16];

        // softmax over 16 neighbors (reduction within each group of 16 lanes)
        const float s = ur[r2n];
        float mx = s;
        mx = fmaxf(mx, __shfl_xor(mx, 1));
        mx = fmaxf(mx, __shfl_xor(mx, 2));
        mx = fmaxf(mx, __shfl_xor(mx, 4));
        mx = fmaxf(mx, __shfl_xor(mx, 8));
        const float e = __expf(s - mx);
        float sum = e;
        sum += __shfl_xor(sum, 1);
        sum += __shfl_xor(sum, 2);
        sum += __shfl_xor(sum, 4);
        sum += __shfl_xor(sum, 8);
        const float attn = e / sum;   // lane holds attn for n = d&15

        // agg_d = sum_n attn[n] * ent_emb[e2[n]][d]
        float agg = 0.f;
        #pragma unroll
        for (int n = 0; n < NNB; ++n) {
            const int en = __builtin_amdgcn_readlane(e2n, n);
            const int ai = __builtin_amdgcn_readlane(__float_as_int(attn), n);
            agg = fmaf(__int_as_float(ai), ent_emb[en * DIMN + d], agg);
        }

        // (sv + agg) @ W0 + b0, sigmoid
        const float x = sv + agg;
        float o = b0d;
        #pragma unroll
        for (int k = 0; k < DIMN; ++k) {
            const int xi = __builtin_amdgcn_readlane(__float_as_int(x), k);
            o = fmaf(__int_as_float(xi), w[k], o);
        }
        h1_sh[m * DIMN + d] = 1.f / (1.f + __expf(-o));
    }
    __syncthreads();

    // ================= iter 0, hop 0 =================
    const float sv0 = ent_emb[vv * DIMN + d];
    const float s0 = ur[r1n];
    float mx0 = s0;
    mx0 = fmaxf(mx0, __shfl_xor(mx0, 1));
    mx0 = fmaxf(mx0, __shfl_xor(mx0, 2));
    mx0 = fmaxf(mx0, __shfl_xor(mx0, 4));
    mx0 = fmaxf(mx0, __shfl_xor(mx0, 8));
    const float e0 = __expf(s0 - mx0);
    float sum0 = e0;
    sum0 += __shfl_xor(sum0, 1);
    sum0 += __shfl_xor(sum0, 2);
    sum0 += __shfl_xor(sum0, 4);
    sum0 += __shfl_xor(sum0, 8);
    const float attn0 = e0 / sum0;   // also the attention for iter1/hop0 (same user, same r1)

    float agg0 = 0.f;
    #pragma unroll
    for (int n = 0; n < NNB; ++n) {
        const int ai = __builtin_amdgcn_readlane(__float_as_int(attn0), n);
        agg0 = fmaf(__int_as_float(ai), sv_sh[n * DIMN + d], agg0);
    }
    const float x0 = sv0 + agg0;
    float o0 = b0d;
    #pragma unroll
    for (int k = 0; k < DIMN; ++k) {
        const int xi = __builtin_amdgcn_readlane(__float_as_int(x0), k);
        o0 = fmaf(__int_as_float(xi), w[k], o0);
    }
    const float h0 = 1.f / (1.f + __expf(-o0));

    // ================= iter 1, hop 0 (tanh) =================
    #pragma unroll
    for (int k = 0; k < DIMN; ++k) w[k] = W1[k * DIMN + d];
    const float b1d = b1[d];

    float agg1 = 0.f;
    #pragma unroll
    for (int n = 0; n < NNB; ++n) {
        const int ai = __builtin_amdgcn_readlane(__float_as_int(attn0), n);
        agg1 = fmaf(__int_as_float(ai), h1_sh[n * DIMN + d], agg1);
    }
    const float x1 = h0 + agg1;
    float o1 = b1d;
    #pragma unroll
    for (int k = 0; k < DIMN; ++k) {
        const int xi = __builtin_amdgcn_readlane(__float_as_int(x1), k);
        o1 = fmaf(__int_as_float(xi), w[k], o1);
    }
    // tanh(x) = 1 - 2/(exp(2x)+1)
    const float item_d = 1.f - 2.f / (1.f + __expf(2.f * o1));

    // ================= final: sigmoid(user . item) =================
    float p = user_d * item_d;
    p += __shfl_xor(p, 1);
    p += __shfl_xor(p, 2);
    p += __shfl_xor(p, 4);
    p += __shfl_xor(p, 8);
    p += __shfl_xor(p, 16);
    p += __shfl_xor(p, 32);
    if (d == 0) out[b] = 1.f / (1.f + __expf(-p));
}

extern "C" void kernel_launch(void* const* d_in, const int* in_sizes, int n_in,
                              void* d_out, int out_size, void* d_ws, size_t ws_size,
                              hipStream_t stream) {
    const int*   u       = (const int*)d_in[0];
    const int*   v       = (const int*)d_in[1];
    const int*   adj     = (const int*)d_in[2];
    const int*   rel_adj = (const int*)d_in[3];
    const float* usr_emb = (const float*)d_in[4];
    const float* ent_emb = (const float*)d_in[5];
    const float* rel_emb = (const float*)d_in[6];
    const float* W0      = (const float*)d_in[7];
    const float* b0      = (const float*)d_in[8];
    const float* W1      = (const float*)d_in[9];
    const float* b1      = (const float*)d_in[10];
    float* out = (float*)d_out;

    const int B = in_sizes[0];   // 4096
    kgs_kernel<<<dim3(B), dim3(64), 0, stream>>>(u, v, adj, rel_adj, usr_emb, ent_emb,
                                                 rel_emb, W0, b0, W1, b1, out);
}